// Round 7
// baseline (1333.205 us; speedup 1.0000x reference)
//
#include <hip/hip_runtime.h>
#include <cstdint>
#include <cstddef>

#define H 256
#define W 256
#define HW (H*W)
#define BATCH 2
#define CIN_TILE 4

typedef __bf16 bf16x8 __attribute__((ext_vector_type(8)));
typedef float f32x4 __attribute__((ext_vector_type(4)));
typedef __attribute__((address_space(1))) uint32_t gu32_t;
typedef __attribute__((address_space(3))) uint32_t lu32_t;

__device__ __forceinline__ void async16(const void* g, void* l) {
  __builtin_amdgcn_global_load_lds((const gu32_t*)g, (lu32_t*)l, 16, 0, 0);
}

__device__ __forceinline__ ushort f2bf(float f) {
  uint u = __float_as_uint(f);
  return (ushort)((u + 0x7FFFu + ((u >> 16) & 1u)) >> 16);
}
__device__ __forceinline__ float lrelu_f(float v) { return v >= 0.f ? v : 0.1f * v; }

// ---------------------------------------------------------------------------
// MFMA implicit-GEMM 3x3 SAME conv.  Activations NHWC bf16 (stride Cin).
// Block: 512 thr (8 waves), tile 64 co x (32x16) px.  152 KB double-buffered
// LDS, one barrier per 32-ci chunk.  THIS ROUND: per-tap register-pipelined
// fragments (issue tap t+1 ds_reads before tap t MFMAs -> counted lgkm
// overlap), sched_barrier(0) pinning the global_load_lds prefetch issue
// early, and setprio(1) around each MFMA cluster (T5).
// Weights prepped [co][tap][Cin_pad] bf16.  blockIdx.z = path.
// EPI 0: bf16 NHWC + lrelu.  EPI 1: head planar fp32.
// ---------------------------------------------------------------------------
#define SWN (2304 * 8)        // ushorts per weight buffer (36 KB)
#define SBN (4 * 640 * 8)     // ushorts per act buffer    (40 KB)
#define DYN_LDS_BYTES (2 * (SWN + SBN) * 2)   // 155648 B (152 KB)

template<int EPI>
__global__ __launch_bounds__(512) void convmm_k(
    const ushort* __restrict__ act, const ushort* __restrict__ wgt,
    const float* __restrict__ bias, ushort* __restrict__ dstb,
    float* __restrict__ dsto, float* __restrict__ dstw,
    const ushort* __restrict__ zpage, int Cin, int CoutS,
    int astride, int wstride, int bstride, int dstride)
{
  extern __shared__ __align__(16) ushort s_dyn[];

  const int z = blockIdx.z;
  act += (size_t)z * astride;
  wgt += (size_t)z * wstride;
  bias += (size_t)z * bstride;
  if constexpr (EPI == 0) dstb += (size_t)z * dstride;
  else { dsto += (size_t)z * (BATCH * 50 * HW); dstw += (size_t)z * (BATCH * 25 * HW); }

  const int tid = threadIdx.x;
  const int sp = blockIdx.x;                    // 0..127
  const int bx = (sp & 7) * 32, by = (sp >> 3) * 16;
  const int co0 = blockIdx.y * 64;
  const int wv = tid >> 6, lane = tid & 63;     // wv 0..7
  const int c = lane & 15, kq = lane >> 4;
  const int oy = wv * 2;

  // staging source offsets (elements); chunk adds c0
  int wsrc[5];
#pragma unroll
  for (int it = 0; it < 5; ++it) {
    int i = tid + it * 512;
    if (i < 2304) {
      int co = i & 63, tk = i >> 6, tap = tk >> 2, kg = tk & 3;
      wsrc[it] = ((co0 + co) * 9 + tap) * Cin + kg * 8;
    } else wsrc[it] = 0;
  }
  int bsrc[5];
#pragma unroll
  for (int it = 0; it < 5; ++it) {
    int i = tid + it * 512;
    int kg = i / 640, px = i - kg * 640;
    int row = px / 34, xx = px - row * 34;
    int gy = by + row - 1, gx = bx + xx - 1;
    bool ok = (px < 612) && ((unsigned)gy < (unsigned)H) && ((unsigned)gx < (unsigned)W);
    bsrc[it] = ok ? ((gy * W + gx) * Cin + kg * 8) : -1;
  }

  auto stage = [&](int buf, int c0) {
    ushort* swc = s_dyn + (buf ? (SWN + SBN) : 0);
    ushort* sbc = swc + SWN;
#pragma unroll
    for (int it = 0; it < 5; ++it)
      if (it < 4 || tid < 2304 - 4 * 512)   // last round: waves 0..3 only
        async16(wgt + wsrc[it] + c0, &swc[(size_t)(tid + it * 512) * 8]);
#pragma unroll
    for (int it = 0; it < 5; ++it) {
      const ushort* g = (bsrc[it] < 0) ? zpage : (act + bsrc[it] + c0);
      async16(g, &sbc[(size_t)(tid + it * 512) * 8]);
    }
  };

  f32x4 acc[4][4];
#pragma unroll
  for (int a = 0; a < 4; ++a)
#pragma unroll
    for (int b2 = 0; b2 < 4; ++b2) acc[a][b2] = (f32x4){0.f, 0.f, 0.f, 0.f};

  // prologue: stage chunk 0 into buf 0 (latency exposed once per kernel)
  stage(0, 0);
  __syncthreads();

  const int nch = Cin >> 5;
  int cur = 0;
  for (int ch = 0; ch < nch; ++ch) {
    if (ch + 1 < nch) stage(cur ^ 1, (ch + 1) << 5);   // prefetch next chunk
    __builtin_amdgcn_sched_barrier(0);   // pin prefetch issue BEFORE compute

    const ushort* swc = s_dyn + (cur ? (SWN + SBN) : 0);
    const ushort* sbc = swc + SWN;

    // per-tap register-pipelined fragments: double-buffered, static indices
    bf16x8 Bf[2][4], Af[2][4];
    {
      // preload tap 0 (dy=-1, dx=-1)
#pragma unroll
      for (int pf = 0; pf < 4; ++pf) {
        int p = (oy + (pf >> 1) + 0) * 34 + (pf & 1) * 16 + 0 + c;
        Bf[0][pf] = *(const bf16x8*)&sbc[(size_t)(kq * 640 + p) * 8];
      }
#pragma unroll
      for (int cf = 0; cf < 4; ++cf)
        Af[0][cf] = *(const bf16x8*)&swc[(size_t)((0 * 4 + kq) * 64 + cf * 16 + c) * 8];
    }

#pragma unroll
    for (int t = 0; t < 9; ++t) {
      const int cb = t & 1, nb = cb ^ 1;
      if (t < 8) {
        const int dy2 = (t + 1) / 3 - 1, dx2 = (t + 1) % 3 - 1;
#pragma unroll
        for (int pf = 0; pf < 4; ++pf) {
          int p = (oy + (pf >> 1) + dy2 + 1) * 34 + (pf & 1) * 16 + dx2 + 1 + c;
          Bf[nb][pf] = *(const bf16x8*)&sbc[(size_t)(kq * 640 + p) * 8];
        }
#pragma unroll
        for (int cf = 0; cf < 4; ++cf)
          Af[nb][cf] = *(const bf16x8*)&swc[(size_t)(((t + 1) * 4 + kq) * 64 + cf * 16 + c) * 8];
      }
      __builtin_amdgcn_s_setprio(1);
#pragma unroll
      for (int cf = 0; cf < 4; ++cf) {
#pragma unroll
        for (int pf = 0; pf < 4; ++pf)
          acc[cf][pf] = __builtin_amdgcn_mfma_f32_16x16x32_bf16(
              Af[cb][cf], Bf[cb][pf], acc[cf][pf], 0, 0, 0);
      }
      __builtin_amdgcn_s_setprio(0);
    }

    // one barrier per chunk: drains this chunk's ds_reads and the prefetch
    // issued (pinned) a full compute-phase ago.
    __syncthreads();
    cur ^= 1;
  }

  const int r4 = kq * 4;
#pragma unroll
  for (int cf = 0; cf < 4; ++cf) {
    int cob = co0 + cf * 16 + r4;
#pragma unroll
    for (int pf = 0; pf < 4; ++pf) {
      int gx2 = bx + (pf & 1) * 16 + c;
      int gy2 = by + oy + (pf >> 1);
      int gpix = gy2 * W + gx2;
      f32x4 v = acc[cf][pf];
      const float4 bv = *(const float4*)&bias[cob];
      if constexpr (EPI == 0) {
        ushort4 ov;
        float f0 = lrelu_f(v[0] + bv.x);
        float f1 = lrelu_f(v[1] + bv.y);
        float f2 = lrelu_f(v[2] + bv.z);
        float f3 = lrelu_f(v[3] + bv.w);
        ov.x = f2bf(f0); ov.y = f2bf(f1); ov.z = f2bf(f2); ov.w = f2bf(f3);
        *(ushort4*)&dstb[(size_t)gpix * CoutS + cob] = ov;
      } else {
        const float* bvp = &bv.x;
#pragma unroll
        for (int r = 0; r < 4; ++r) {
          int coa = cob + r;
          if (coa < 75) {
            float f = v[r] + bvp[r];
            if (coa < 50) dsto[(size_t)coa * HW + gpix] = f;
            else          dstw[(size_t)(coa - 50) * HW + gpix] = f;
          }
        }
      }
    }
  }
}

// ---------------------------------------------------------------------------
// Small fp32 extractor conv (planar), batched over z = frame*2 + batch
// ---------------------------------------------------------------------------
template<int CIN>
__global__ __launch_bounds__(256) void conv_fr_k(
    const float* __restrict__ sA, const float* __restrict__ sB, int mode,
    const float* __restrict__ wgt, const float* __restrict__ bias,
    float* __restrict__ dst)
{
  const int z = blockIdx.y;
  const float* src = (mode == 0)
      ? (((z >> 1) ? sB : sA) + (size_t)(z & 1) * 3 * HW)
      : (sA + (size_t)z * 16 * HW);
  float* out = dst + (size_t)z * 16 * HW;

  const int sp = blockIdx.x;
  const int bx = (sp & 7) * 32, by = (sp >> 3) * 32;
  const int tid = threadIdx.x;
  const int tx = tid & 15, ty = tid >> 4;

  __shared__ float s_in[CIN_TILE][34][36];
  float acc[16][2][2];
#pragma unroll
  for (int co = 0; co < 16; ++co) {
    acc[co][0][0] = 0.f; acc[co][0][1] = 0.f;
    acc[co][1][0] = 0.f; acc[co][1][1] = 0.f;
  }

  for (int c0 = 0; c0 < CIN; c0 += CIN_TILE) {
    __syncthreads();
    const int nst = CIN_TILE * 34 * 34;
    for (int i = tid; i < nst; i += 256) {
      int ci = i / (34 * 34);
      int r = i - ci * (34 * 34);
      int yy = r / 34;
      int xx = r - yy * 34;
      int gy = by + yy - 1, gx = bx + xx - 1;
      int cc = c0 + ci;
      float v = 0.f;
      if (cc < CIN && (unsigned)gy < (unsigned)H && (unsigned)gx < (unsigned)W)
        v = src[(size_t)cc * HW + gy * W + gx];
      s_in[ci][yy][xx] = v;
    }
    __syncthreads();

    const int cmax = (CIN - c0 < CIN_TILE) ? (CIN - c0) : CIN_TILE;
    for (int ci = 0; ci < cmax; ++ci) {
      float win[4][4];
#pragma unroll
      for (int iy = 0; iy < 4; ++iy)
#pragma unroll
        for (int ix = 0; ix < 4; ++ix)
          win[iy][ix] = s_in[ci][2 * ty + iy][2 * tx + ix];
#pragma unroll
      for (int co = 0; co < 16; ++co) {
        const float* wp = wgt + ((size_t)co * CIN + (c0 + ci)) * 9;
        float w0 = wp[0], w1 = wp[1], w2 = wp[2];
        float w3 = wp[3], w4 = wp[4], w5 = wp[5];
        float w6 = wp[6], w7 = wp[7], w8 = wp[8];
#pragma unroll
        for (int py = 0; py < 2; ++py)
#pragma unroll
          for (int px = 0; px < 2; ++px) {
            float s = acc[co][py][px];
            s += w0 * win[py + 0][px + 0];
            s += w1 * win[py + 0][px + 1];
            s += w2 * win[py + 0][px + 2];
            s += w3 * win[py + 1][px + 0];
            s += w4 * win[py + 1][px + 1];
            s += w5 * win[py + 1][px + 2];
            s += w6 * win[py + 2][px + 0];
            s += w7 * win[py + 2][px + 1];
            s += w8 * win[py + 2][px + 2];
            acc[co][py][px] = s;
          }
      }
    }
  }
#pragma unroll
  for (int co = 0; co < 16; ++co) {
    float bv = bias[co];
#pragma unroll
    for (int py = 0; py < 2; ++py)
#pragma unroll
      for (int px = 0; px < 2; ++px)
        out[(size_t)co * HW + (size_t)(by + 2 * ty + py) * W + (bx + 2 * tx + px)] =
            lrelu_f(acc[co][py][px] + bv);
  }
}

// ---------------------------------------------------------------------------
// Build combined NHWC bf16 [HW][288] for batch item b
// ---------------------------------------------------------------------------
__global__ __launch_bounds__(256) void pack_k(
    const float* __restrict__ feat1, const float* __restrict__ feat2,
    const float* __restrict__ corr, const float* __restrict__ fr,
    ushort* __restrict__ comb, int b)
{
  int gid = blockIdx.x * 256 + threadIdx.x;   // over 9*HW
  int chunk = gid / HW;
  int p = gid - chunk * HW;
  int c0 = chunk * 32;

  uint u[16];
#pragma unroll
  for (int j = 0; j < 32; j += 2) {
    float f[2];
#pragma unroll
    for (int q = 0; q < 2; ++q) {
      int cc = c0 + j + q;
      float v;
      if (cc < 32)       v = feat1[(size_t)(b * 32 + cc) * HW + p];
      else if (cc < 64)  v = feat2[(size_t)(b * 32 + cc - 32) * HW + p];
      else if (cc < 233) v = corr[(size_t)(b * 169 + cc - 64) * HW + p];
      else if (cc < 249) v = fr[(size_t)(b * 16 + (cc - 233)) * HW + p];
      else if (cc < 265) v = fr[(size_t)((2 + b) * 16 + (cc - 249)) * HW + p];
      else if (cc == 265) v = 0.5f;
      else               v = 0.f;
      f[q] = v;
    }
    u[j >> 1] = (uint)f2bf(f[0]) | ((uint)f2bf(f[1]) << 16);
  }
  uint4* dst = (uint4*)&comb[(size_t)p * 288 + c0];
#pragma unroll
  for (int q = 0; q < 4; ++q) {
    uint4 t;
    t.x = u[q * 4 + 0]; t.y = u[q * 4 + 1]; t.z = u[q * 4 + 2]; t.w = u[q * 4 + 3];
    dst[q] = t;
  }
}

// ---------------------------------------------------------------------------
// Fused weight prep: all conv weight transforms in one launch.
// ---------------------------------------------------------------------------
struct PrepSeg { const float* src; ushort* dst; int O, I, Ipad; };
struct PrepArgs { PrepSeg s[13]; int pre[14]; };

__global__ __launch_bounds__(256) void prep_all_k(PrepArgs a)
{
  int gid = blockIdx.x * 256 + threadIdx.x;
  if (gid >= a.pre[13]) return;
  int si = 0;
  while (gid >= a.pre[si + 1]) ++si;
  int idx = gid - a.pre[si];
  const PrepSeg sg = a.s[si];
  int i = idx % sg.Ipad;
  int r = idx / sg.Ipad;
  int tap = r % 9;
  int o = r / 9;
  float v = (i < sg.I) ? sg.src[((size_t)o * sg.I + i) * 9 + tap] : 0.f;
  sg.dst[idx] = f2bf(v);
}

// fused bias copies: contiguous per-path bias buffers + head bias build
__global__ __launch_bounds__(256) void bias_all_k(
    const float* kb1_0, const float* kb1_1, const float* kb2_0, const float* kb2_1,
    const float* kb3_0, const float* kb3_1,
    const float* ob0, const float* wb0, const float* ob1, const float* wb1,
    float* bb1, float* bb2, float* bb3, float* bbh)
{
  int yq = blockIdx.y;
  int i = threadIdx.x;
  switch (yq) {
    case 0: bb1[i] = kb1_0[i]; break;
    case 1: bb1[256 + i] = kb1_1[i]; break;
    case 2: bb2[i] = kb2_0[i]; break;
    case 3: bb2[256 + i] = kb2_1[i]; break;
    case 4: if (i < 128) bb3[i] = kb3_0[i]; break;
    case 5: if (i < 128) bb3[128 + i] = kb3_1[i]; break;
    case 6: if (i < 128) bbh[i]       = (i < 50) ? ob0[i] : ((i < 75) ? wb0[i - 50] : 0.f); break;
    case 7: if (i < 128) bbh[128 + i] = (i < 50) ? ob1[i] : ((i < 75) ? wb1[i - 50] : 0.f); break;
  }
}

// blend second conv: NHWC bf16 64ch -> sigmoid fp32 planar
__global__ __launch_bounds__(256) void blend2_k(
    const ushort* __restrict__ actD, const float* __restrict__ wgt,
    const float* __restrict__ b2, float* __restrict__ outp)
{
  int p = blockIdx.x * 256 + threadIdx.x;
  int y = p >> 8, x = p & 255;
  float acc = b2[0];
  for (int dy = -1; dy <= 1; ++dy) {
    int gy = y + dy;
    if ((unsigned)gy >= (unsigned)H) continue;
    for (int dx = -1; dx <= 1; ++dx) {
      int gx = x + dx;
      if ((unsigned)gx >= (unsigned)W) continue;
      int tap = (dy + 1) * 3 + (dx + 1);
      const ushort* rowp = actD + (size_t)(gy * W + gx) * 64;
#pragma unroll
      for (int c8 = 0; c8 < 8; ++c8) {
        uint4 v = *(const uint4*)&rowp[c8 * 8];
        const uint* vv = &v.x;
#pragma unroll
        for (int q = 0; q < 4; ++q) {
          float f0 = __uint_as_float(vv[q] << 16);
          float f1 = __uint_as_float(vv[q] & 0xFFFF0000u);
          int ci = c8 * 8 + q * 2;
          acc += f0 * wgt[ci * 9 + tap];
          acc += f1 * wgt[(ci + 1) * 9 + tap];
        }
      }
    }
  }
  outp[p] = 1.f / (1.f + expf(-acc));
}

// softmax over 25 channels, both paths in one launch (grid.y = path)
__global__ __launch_bounds__(256) void softmax25_k(float* __restrict__ w1,
                                                   float* __restrict__ w2)
{
  float* wr = blockIdx.y ? w2 : w1;
  int p = blockIdx.x * 256 + threadIdx.x;
  if (p >= HW) return;
  float v[25];
  float m = -1e30f;
#pragma unroll
  for (int k = 0; k < 25; ++k) {
    v[k] = wr[(size_t)k * HW + p];
    m = fmaxf(m, v[k]);
  }
  float s = 0.f;
#pragma unroll
  for (int k = 0; k < 25; ++k) {
    v[k] = expf(v[k] - m);
    s += v[k];
  }
  float inv = 1.f / s;
#pragma unroll
  for (int k = 0; k < 25; ++k)
    wr[(size_t)k * HW + p] = v[k] * inv;
}

__device__ __forceinline__ void cubic4(float t, float* cw)
{
  const float A_ = -0.75f;
  float t2 = t * t;
  cw[1] = ((A_ + 2.f) * t - (A_ + 3.f)) * t2 + 1.f;
  float s = 1.f - t;
  cw[2] = ((A_ + 2.f) * s - (A_ + 3.f)) * (s * s) + 1.f;
  float u = t + 1.f;
  cw[0] = ((A_ * u - 5.f * A_) * u + 8.f * A_) * u - 4.f * A_;
  float v = 2.f - t;
  cw[3] = ((A_ * v - 5.f * A_) * v + 8.f * A_) * v - 4.f * A_;
}

// ---------------------------------------------------------------------------
// AdaCoF sampling + blend, LDS-tiled.  Block = 256 thr, tile 64x4 px,
// halo 8; both frames staged as float4 (3ch+pad) -> 51.2 KB LDS.
// ---------------------------------------------------------------------------
#define ATW 64
#define ATH 4
#define AHL 8
#define AROWS (ATH + 2*AHL)   // 20
#define ACOLS (ATW + 2*AHL)   // 80

__global__ __launch_bounds__(256) void adacof_final_k(
    const float* __restrict__ frame1, const float* __restrict__ frame2,
    const float* __restrict__ off1, const float* __restrict__ off2,
    const float* __restrict__ wt1, const float* __restrict__ wt2,
    const float* __restrict__ blend, float* __restrict__ outp)
{
  __shared__ __align__(16) float4 s_img[2 * AROWS * ACOLS];   // 51.2 KB

  const int tid = threadIdx.x;
  int t = blockIdx.x;
  const int tilesPerImg = (H / ATH) * (W / ATW);   // 256
  const int b = t / tilesPerImg; t -= b * tilesPerImg;
  const int by = (t >> 2) * ATH, bx = (t & 3) * ATW;
  const int ty = tid >> 6, txx = tid & 63;
  const int y = by + ty, x = bx + txx;
  const int p = y * W + x;
  const int tx0 = bx - AHL, ty0 = by - AHL;

  const float* f1 = frame1 + (size_t)b * 3 * HW;
  const float* f2 = frame2 + (size_t)b * 3 * HW;

  for (int i = tid; i < AROWS * ACOLS; i += 256) {
    int r = i / ACOLS, cc = i - r * ACOLS;
    int gy = min(max(ty0 + r, 0), H - 1);
    int gx = min(max(tx0 + cc, 0), W - 1);
    int q = gy * W + gx;
    float4 v1, v2;
    v1.x = f1[q]; v1.y = f1[HW + q]; v1.z = f1[2 * HW + q]; v1.w = 0.f;
    v2.x = f2[q]; v2.y = f2[HW + q]; v2.z = f2[2 * HW + q]; v2.w = 0.f;
    s_img[i] = v1;
    s_img[AROWS * ACOLS + i] = v2;
  }
  __syncthreads();

  float a1[3] = {0.f, 0.f, 0.f};
  float a2[3] = {0.f, 0.f, 0.f};

  const size_t ob1 = (size_t)b * 50 * HW, wb1 = (size_t)b * 25 * HW;

#pragma unroll 2
  for (int k = 0; k < 25; ++k) {
#pragma unroll
    for (int fr = 0; fr < 2; ++fr) {
      const float* off = fr ? off2 : off1;
      const float* wts = fr ? wt2 : wt1;
      const float* img = fr ? f2 : f1;
      float* acc = fr ? a2 : a1;

      float dx = off[ob1 + (size_t)(2 * k) * HW + p];
      float dy = off[ob1 + (size_t)(2 * k + 1) * HW + p];
      float wk = wts[wb1 + (size_t)k * HW + p];
      float sx = (float)x + dx, sy = (float)y + dy;
      float x0f = floorf(sx), y0f = floorf(sy);
      float tx = sx - x0f, tyf = sy - y0f;
      float wx[4], wy[4];
      cubic4(tx, wx);
      cubic4(tyf, wy);
      int ix0 = (int)x0f, iy0 = (int)y0f;

      bool inT = (ix0 - 1 >= tx0) && (ix0 + 2 <= tx0 + ACOLS - 1) &&
                 (iy0 - 1 >= ty0) && (iy0 + 2 <= ty0 + AROWS - 1);
      if (__builtin_expect(inT, 1)) {
        const float4* base = &s_img[(size_t)fr * AROWS * ACOLS +
                                    (iy0 - 1 - ty0) * ACOLS + (ix0 - 1 - tx0)];
#pragma unroll
        for (int i = 0; i < 4; ++i) {
#pragma unroll
          for (int j = 0; j < 4; ++j) {
            float wf = wy[i] * wx[j] * wk;
            float4 v = base[i * ACOLS + j];
            acc[0] += v.x * wf;
            acc[1] += v.y * wf;
            acc[2] += v.z * wf;
          }
        }
      } else {
        int xi[4], yi[4];
#pragma unroll
        for (int i = 0; i < 4; ++i) {
          xi[i] = min(max(ix0 + i - 1, 0), W - 1);
          yi[i] = min(max(iy0 + i - 1, 0), H - 1);
        }
#pragma unroll
        for (int i = 0; i < 4; ++i) {
#pragma unroll
          for (int j = 0; j < 4; ++j) {
            float wf = wy[i] * wx[j] * wk;
            int q = yi[i] * W + xi[j];
            acc[0] += img[q] * wf;
            acc[1] += img[HW + q] * wf;
            acc[2] += img[2 * HW + q] * wf;
          }
        }
      }
    }
  }

  float bl = blend[(size_t)b * HW + p];
#pragma unroll
  for (int c3 = 0; c3 < 3; ++c3)
    outp[((size_t)b * 3 + c3) * HW + p] = bl * a1[c3] + (1.f - bl) * a2[c3];
}

// ---------------------------------------------------------------------------
extern "C" void kernel_launch(void* const* d_in, const int* in_sizes, int n_in,
                              void* d_out, int out_size, void* d_ws, size_t ws_size,
                              hipStream_t stream)
{
  const float* frame1 = (const float*)d_in[0];
  const float* frame2 = (const float*)d_in[1];
  const float* feat1  = (const float*)d_in[2];
  const float* feat2  = (const float*)d_in[3];
  const float* corr   = (const float*)d_in[4];
  const float* fr_w1  = (const float*)d_in[5];
  const float* fr_b1  = (const float*)d_in[6];
  const float* fr_w2  = (const float*)d_in[7];
  const float* fr_b2  = (const float*)d_in[8];

  const float* kw1[2] = {(const float*)d_in[9],  (const float*)d_in[19]};
  const float* kb1[2] = {(const float*)d_in[10], (const float*)d_in[20]};
  const float* kw2[2] = {(const float*)d_in[11], (const float*)d_in[21]};
  const float* kb2[2] = {(const float*)d_in[12], (const float*)d_in[22]};
  const float* kw3[2] = {(const float*)d_in[13], (const float*)d_in[23]};
  const float* kb3[2] = {(const float*)d_in[14], (const float*)d_in[24]};
  const float* kow[2] = {(const float*)d_in[15], (const float*)d_in[25]};
  const float* kob[2] = {(const float*)d_in[16], (const float*)d_in[26]};
  const float* kww[2] = {(const float*)d_in[17], (const float*)d_in[27]};
  const float* kwb[2] = {(const float*)d_in[18], (const float*)d_in[28]};

  const float* bl_w1 = (const float*)d_in[29];
  const float* bl_b1 = (const float*)d_in[30];
  const float* bl_w2 = (const float*)d_in[31];
  const float* bl_b2 = (const float*)d_in[32];

  float* out = (float*)d_out;
  float* o_out   = out;
  float* o_blend = o_out   + (size_t)BATCH * 3 * HW;
  float* o_off1  = o_blend + (size_t)BATCH * 1 * HW;
  float* o_off2  = o_off1  + (size_t)BATCH * 50 * HW;
  float* o_w1    = o_off2  + (size_t)BATCH * 50 * HW;
  float* o_w2    = o_w1    + (size_t)BATCH * 25 * HW;

  // allow 152 KB dynamic LDS on the conv kernels (capture-safe, idempotent)
  hipFuncSetAttribute((const void*)convmm_k<0>,
                      hipFuncAttributeMaxDynamicSharedMemorySize, DYN_LDS_BYTES);
  hipFuncSetAttribute((const void*)convmm_k<1>,
                      hipFuncAttributeMaxDynamicSharedMemorySize, DYN_LDS_BYTES);

  // ---- workspace layout (sizes all multiples of 256 B) ----
  size_t off = 0;
  char* wsb = (char*)d_ws;
  auto alloc = [&](size_t bytes) -> void* {
    void* pp = wsb + off;
    off += (bytes + 255) & ~(size_t)255;
    return pp;
  };
  const size_t NEED_MERGED = 212700000;
  const bool merged = ws_size >= NEED_MERGED;
  const int NZ = merged ? 2 : 1;

  ushort* zpage = (ushort*)alloc(512);
  ushort* wp1   = (ushort*)alloc((size_t)2 * 256 * 9 * 288 * 2);
  ushort* wp2   = (ushort*)alloc((size_t)2 * 256 * 9 * 256 * 2);
  ushort* wp3   = (ushort*)alloc((size_t)2 * 128 * 9 * 256 * 2);
  ushort* wph   = (ushort*)alloc((size_t)2 * 128 * 9 * 128 * 2);
  ushort* wpb   = (ushort*)alloc((size_t)64 * 9 * 288 * 2);
  float*  bb1   = (float*)alloc(2 * 256 * 4);
  float*  bb2   = (float*)alloc(2 * 256 * 4);
  float*  bb3   = (float*)alloc(2 * 128 * 4);
  float*  bbh   = (float*)alloc(2 * 128 * 4);
  float*  tmp4  = (float*)alloc((size_t)4 * 16 * HW * 4);
  float*  frbuf = (float*)alloc((size_t)4 * 16 * HW * 4);
  ushort* comb  = (ushort*)alloc((size_t)HW * 288 * 2);
  ushort* actA  = (ushort*)alloc((size_t)NZ * HW * 256 * 2);
  ushort* actB  = (ushort*)alloc((size_t)NZ * HW * 256 * 2);

  dim3 blk(256);
  dim3 cblk(512);

  // ---- fused prep ----
  hipMemsetAsync(zpage, 0, 512, stream);
  {
    PrepArgs pa;
    const int W1 = 256 * 9 * 288, W2 = 256 * 9 * 256, W3 = 128 * 9 * 256;
    const int OW = 50 * 9 * 128, WW = 25 * 9 * 128, ZW = 53 * 9 * 128;
    const int WB = 64 * 9 * 288;
    const int HP = 128 * 9 * 128;
    PrepSeg segs[13] = {
      {kw1[0], wp1,                    256, 266, 288},
      {kw1[1], wp1 + W1,               256, 266, 288},
      {kw2[0], wp2,                    256, 256, 256},
      {kw2[1], wp2 + W2,               256, 256, 256},
      {kw3[0], wp3,                    128, 256, 256},
      {kw3[1], wp3 + W3,               128, 256, 256},
      {kow[0], wph,                     50, 128, 128},
      {kww[0], wph + OW,                25, 128, 128},
      {nullptr, wph + OW + WW,          53,   0, 128},
      {kow[1], wph + HP,                50, 128, 128},
      {kww[1], wph + HP + OW,           25, 128, 128},
      {nullptr, wph + HP + OW + WW,     53,   0, 128},
      {bl_w1,  wpb,                     64, 266, 288},
    };
    int tots[13] = {W1, W1, W2, W2, W3, W3, OW, WW, ZW, OW, WW, ZW, WB};
    pa.pre[0] = 0;
    for (int s = 0; s < 13; ++s) { pa.s[s] = segs[s]; pa.pre[s + 1] = pa.pre[s] + tots[s]; }
    int nblk = (pa.pre[13] + 255) / 256;
    prep_all_k<<<dim3(nblk), blk, 0, stream>>>(pa);
  }
  bias_all_k<<<dim3(1, 8), blk, 0, stream>>>(kb1[0], kb1[1], kb2[0], kb2[1],
                                             kb3[0], kb3[1], kob[0], kwb[0],
                                             kob[1], kwb[1], bb1, bb2, bb3, bbh);

  // ---- frame extractor ----
  conv_fr_k<3><<<dim3(64, 4), blk, 0, stream>>>(frame1, frame2, 0, fr_w1, fr_b1, tmp4);
  conv_fr_k<16><<<dim3(64, 4), blk, 0, stream>>>(tmp4, nullptr, 1, fr_w2, fr_b2, frbuf);

  const int W1 = 256 * 9 * 288, W2 = 256 * 9 * 256, W3 = 128 * 9 * 256;
  const int HP = 128 * 9 * 128;

  for (int b = 0; b < BATCH; ++b) {
    pack_k<<<dim3(9 * HW / 256), blk, 0, stream>>>(feat1, feat2, corr, frbuf, comb, b);

    for (int pp = 0; pp < 2 / NZ; ++pp) {
      const size_t po = pp;
      convmm_k<0><<<dim3(128, 4, NZ), cblk, DYN_LDS_BYTES, stream>>>(
          comb, wp1 + po * W1, bb1 + po * 256, actA + po * (size_t)HW * 256,
          nullptr, nullptr, zpage, 288, 256, 0, W1, 256, HW * 256);
      convmm_k<0><<<dim3(128, 4, NZ), cblk, DYN_LDS_BYTES, stream>>>(
          actA + po * (size_t)HW * 256, wp2 + po * W2, bb2 + po * 256,
          actB + po * (size_t)HW * 256,
          nullptr, nullptr, zpage, 256, 256, HW * 256, W2, 256, HW * 256);
      convmm_k<0><<<dim3(128, 2, NZ), cblk, DYN_LDS_BYTES, stream>>>(
          actB + po * (size_t)HW * 256, wp3 + po * W3, bb3 + po * 128,
          actA + po * (size_t)HW * 128,
          nullptr, nullptr, zpage, 256, 128, HW * 256, W3, 128, HW * 128);
      convmm_k<1><<<dim3(128, 2, NZ), cblk, DYN_LDS_BYTES, stream>>>(
          actA + po * (size_t)HW * 128, wph + po * HP, bbh + po * 128, nullptr,
          o_off1 + (size_t)b * 50 * HW + po * (size_t)BATCH * 50 * HW,
          o_w1 + (size_t)b * 25 * HW + po * (size_t)BATCH * 25 * HW,
          zpage, 128, 0, HW * 128, HP, 128, 0);
    }
    softmax25_k<<<dim3(HW / 256, 2), blk, 0, stream>>>(
        o_w1 + (size_t)b * 25 * HW, o_w2 + (size_t)b * 25 * HW);

    convmm_k<0><<<dim3(128, 1, 1), cblk, DYN_LDS_BYTES, stream>>>(
        comb, wpb, bl_b1, actB, nullptr, nullptr, zpage, 288, 64, 0, 0, 0, 0);
    blend2_k<<<dim3(HW / 256), blk, 0, stream>>>(actB, bl_w2, bl_b2,
                                                 o_blend + (size_t)b * HW);
  }

  adacof_final_k<<<dim3(BATCH * (H / ATH) * (W / ATW)), blk, 0, stream>>>(
      frame1, frame2, o_off1, o_off2, o_w1, o_w2, o_blend, o_out);
}

// Round 8
// 1288.225 us; speedup vs baseline: 1.0349x; 1.0349x over previous
//
#include <hip/hip_runtime.h>
#include <cstdint>
#include <cstddef>

#define H 256
#define W 256
#define HW (H*W)
#define BATCH 2
#define CIN_TILE 4

typedef __bf16 bf16x8 __attribute__((ext_vector_type(8)));
typedef float f32x4 __attribute__((ext_vector_type(4)));
typedef __attribute__((address_space(1))) uint32_t gu32_t;
typedef __attribute__((address_space(3))) uint32_t lu32_t;

__device__ __forceinline__ void async16(const void* g, void* l) {
  __builtin_amdgcn_global_load_lds((const gu32_t*)g, (lu32_t*)l, 16, 0, 0);
}

__device__ __forceinline__ ushort f2bf(float f) {
  uint u = __float_as_uint(f);
  return (ushort)((u + 0x7FFFu + ((u >> 16) & 1u)) >> 16);
}
__device__ __forceinline__ float lrelu_f(float v) { return v >= 0.f ? v : 0.1f * v; }

// ---------------------------------------------------------------------------
// MFMA implicit-GEMM 3x3 SAME conv.  Activations NHWC bf16 (stride Cin).
// Block: 512 thr (8 waves), tile 64 co x (32x16) px, 152 KB double-buffered
// LDS, one barrier per 32-ci chunk.  Inner loop: 9 tap-PHASES, each
//   {asm ds_read_b128 x8 for tap t+1 -> s_waitcnt lgkmcnt(8) ->
//    sched_barrier(0) -> setprio(1) 16xMFMA setprio(0)}
// so the current phase's LDS reads run on the LDS pipe WHILE the previous
// phase's MFMAs run on the matrix pipe (within-wave overlap, rule #18
// inline-asm + counted lgkm so the compiler cannot re-serialize).
// Weights prepped [co][tap][Cin_pad] bf16.  blockIdx.z = path.
// EPI 0: bf16 NHWC + lrelu.  EPI 1: head planar fp32.
// ---------------------------------------------------------------------------
#define SWN (2304 * 8)        // ushorts per weight buffer (36 KB)
#define SBN (4 * 640 * 8)     // ushorts per act buffer    (40 KB)
#define DYN_LDS_BYTES (2 * (SWN + SBN) * 2)   // 155648 B (152 KB)

// 8 fragment reads for tap tt into register bank bb (compile-time tt, bb)
#define ISSUE_TAP(tt, bb)                                                     \
  do {                                                                        \
    asm volatile("ds_read_b128 %0, %1 offset:%c2"                             \
                 : "=v"(Afr[bb][0]) : "v"(aA0), "i"((tt) * 4096));            \
    asm volatile("ds_read_b128 %0, %1 offset:%c2"                             \
                 : "=v"(Afr[bb][1]) : "v"(aA1), "i"((tt) * 4096));            \
    asm volatile("ds_read_b128 %0, %1 offset:%c2"                             \
                 : "=v"(Afr[bb][2]) : "v"(aA2), "i"((tt) * 4096));            \
    asm volatile("ds_read_b128 %0, %1 offset:%c2"                             \
                 : "=v"(Afr[bb][3]) : "v"(aA3), "i"((tt) * 4096));            \
    asm volatile("ds_read_b128 %0, %1 offset:%c2"                             \
                 : "=v"(Bfr[bb][0]) : "v"(aB0),                               \
                   "i"(((((tt) / 3) * 34) + ((tt) % 3)) * 16));               \
    asm volatile("ds_read_b128 %0, %1 offset:%c2"                             \
                 : "=v"(Bfr[bb][1]) : "v"(aB1),                               \
                   "i"(((((tt) / 3) * 34) + ((tt) % 3)) * 16));               \
    asm volatile("ds_read_b128 %0, %1 offset:%c2"                             \
                 : "=v"(Bfr[bb][2]) : "v"(aB2),                               \
                   "i"(((((tt) / 3) * 34) + ((tt) % 3)) * 16));               \
    asm volatile("ds_read_b128 %0, %1 offset:%c2"                             \
                 : "=v"(Bfr[bb][3]) : "v"(aB3),                               \
                   "i"(((((tt) / 3) * 34) + ((tt) % 3)) * 16));               \
  } while (0)

template<int EPI>
__global__ __launch_bounds__(512) void convmm_k(
    const ushort* __restrict__ act, const ushort* __restrict__ wgt,
    const float* __restrict__ bias, ushort* __restrict__ dstb,
    float* __restrict__ dsto, float* __restrict__ dstw,
    const ushort* __restrict__ zpage, int Cin, int CoutS,
    int astride, int wstride, int bstride, int dstride)
{
  extern __shared__ __align__(16) ushort s_dyn[];

  const int z = blockIdx.z;
  act += (size_t)z * astride;
  wgt += (size_t)z * wstride;
  bias += (size_t)z * bstride;
  if constexpr (EPI == 0) dstb += (size_t)z * dstride;
  else { dsto += (size_t)z * (BATCH * 50 * HW); dstw += (size_t)z * (BATCH * 25 * HW); }

  const int tid = threadIdx.x;
  const int sp = blockIdx.x;                    // 0..127
  const int bx = (sp & 7) * 32, by = (sp >> 3) * 16;
  const int co0 = blockIdx.y * 64;
  const int wv = tid >> 6, lane = tid & 63;     // wv 0..7
  const int c = lane & 15, kq = lane >> 4;
  const int oy = wv * 2;

  // staging source offsets (elements); chunk adds c0
  int wsrc[5];
#pragma unroll
  for (int it = 0; it < 5; ++it) {
    int i = tid + it * 512;
    if (i < 2304) {
      int co = i & 63, tk = i >> 6, tap = tk >> 2, kg = tk & 3;
      wsrc[it] = ((co0 + co) * 9 + tap) * Cin + kg * 8;
    } else wsrc[it] = 0;
  }
  int bsrc[5];
#pragma unroll
  for (int it = 0; it < 5; ++it) {
    int i = tid + it * 512;
    int kg = i / 640, px = i - kg * 640;
    int row = px / 34, xx = px - row * 34;
    int gy = by + row - 1, gx = bx + xx - 1;
    bool ok = (px < 612) && ((unsigned)gy < (unsigned)H) && ((unsigned)gx < (unsigned)W);
    bsrc[it] = ok ? ((gy * W + gx) * Cin + kg * 8) : -1;
  }

  auto stage = [&](int buf, int c0) {
    ushort* swc = s_dyn + (buf ? (SWN + SBN) : 0);
    ushort* sbc = swc + SWN;
#pragma unroll
    for (int it = 0; it < 5; ++it)
      if (it < 4 || tid < 2304 - 4 * 512)   // last round: waves 0..3 only
        async16(wgt + wsrc[it] + c0, &swc[(size_t)(tid + it * 512) * 8]);
#pragma unroll
    for (int it = 0; it < 5; ++it) {
      const ushort* g = (bsrc[it] < 0) ? zpage : (act + bsrc[it] + c0);
      async16(g, &sbc[(size_t)(tid + it * 512) * 8]);
    }
  };

  f32x4 acc[4][4];
#pragma unroll
  for (int a = 0; a < 4; ++a)
#pragma unroll
    for (int b2 = 0; b2 < 4; ++b2) acc[a][b2] = (f32x4){0.f, 0.f, 0.f, 0.f};

  // prologue: stage chunk 0 into buf 0 (latency exposed once per kernel)
  stage(0, 0);
  __syncthreads();

  // 32-bit LDS byte address of the dynamic-LDS base (AS3 pointers are 32-bit)
  const uint sdyn_base = (uint)(uintptr_t)(lu32_t*)s_dyn;

  const int nch = Cin >> 5;
  int cur = 0;
  for (int ch = 0; ch < nch; ++ch) {
    if (ch + 1 < nch) stage(cur ^ 1, (ch + 1) << 5);   // prefetch next chunk
    __builtin_amdgcn_sched_barrier(0);   // pin prefetch issue before compute

    const uint swoff = sdyn_base + (cur ? (uint)((SWN + SBN) * 2) : 0u);
    const uint sboff = swoff + (uint)(SWN * 2);
    // tap-0 base addresses (per-tap deltas are compile-time offset: imms)
    const uint aA0 = swoff + (uint)((kq * 64 + 0 * 16 + c) * 16);
    const uint aA1 = swoff + (uint)((kq * 64 + 1 * 16 + c) * 16);
    const uint aA2 = swoff + (uint)((kq * 64 + 2 * 16 + c) * 16);
    const uint aA3 = swoff + (uint)((kq * 64 + 3 * 16 + c) * 16);
    const uint aB0 = sboff + (uint)((kq * 640 + (oy + 0) * 34 + 0 * 16 + c) * 16);
    const uint aB1 = sboff + (uint)((kq * 640 + (oy + 0) * 34 + 1 * 16 + c) * 16);
    const uint aB2 = sboff + (uint)((kq * 640 + (oy + 1) * 34 + 0 * 16 + c) * 16);
    const uint aB3 = sboff + (uint)((kq * 640 + (oy + 1) * 34 + 1 * 16 + c) * 16);

    bf16x8 Afr[2][4], Bfr[2][4];
    ISSUE_TAP(0, 0);

#pragma unroll
    for (int t = 0; t < 9; ++t) {
      if (t < 8) {
        switch (t + 1) {   // compile-time tap index for the offset imms
          case 1: ISSUE_TAP(1, 1); break;
          case 2: ISSUE_TAP(2, 0); break;
          case 3: ISSUE_TAP(3, 1); break;
          case 4: ISSUE_TAP(4, 0); break;
          case 5: ISSUE_TAP(5, 1); break;
          case 6: ISSUE_TAP(6, 0); break;
          case 7: ISSUE_TAP(7, 1); break;
          case 8: ISSUE_TAP(8, 0); break;
        }
        asm volatile("s_waitcnt lgkmcnt(8)" ::: "memory");
      } else {
        asm volatile("s_waitcnt lgkmcnt(0)" ::: "memory");
      }
      __builtin_amdgcn_sched_barrier(0);
      __builtin_amdgcn_s_setprio(1);
#pragma unroll
      for (int cf = 0; cf < 4; ++cf) {
#pragma unroll
        for (int pf = 0; pf < 4; ++pf)
          acc[cf][pf] = __builtin_amdgcn_mfma_f32_16x16x32_bf16(
              Afr[t & 1][cf], Bfr[t & 1][pf], acc[cf][pf], 0, 0, 0);
      }
      __builtin_amdgcn_s_setprio(0);
      __builtin_amdgcn_sched_barrier(0);
    }

    // one barrier per chunk: drains this chunk's prefetch (issued a full
    // compute-phase ago) so buffers may swap.
    __syncthreads();
    cur ^= 1;
  }

  const int r4 = kq * 4;
#pragma unroll
  for (int cf = 0; cf < 4; ++cf) {
    int cob = co0 + cf * 16 + r4;
#pragma unroll
    for (int pf = 0; pf < 4; ++pf) {
      int gx2 = bx + (pf & 1) * 16 + c;
      int gy2 = by + oy + (pf >> 1);
      int gpix = gy2 * W + gx2;
      f32x4 v = acc[cf][pf];
      const float4 bv = *(const float4*)&bias[cob];
      if constexpr (EPI == 0) {
        ushort4 ov;
        float f0 = lrelu_f(v[0] + bv.x);
        float f1 = lrelu_f(v[1] + bv.y);
        float f2 = lrelu_f(v[2] + bv.z);
        float f3 = lrelu_f(v[3] + bv.w);
        ov.x = f2bf(f0); ov.y = f2bf(f1); ov.z = f2bf(f2); ov.w = f2bf(f3);
        *(ushort4*)&dstb[(size_t)gpix * CoutS + cob] = ov;
      } else {
        const float* bvp = &bv.x;
#pragma unroll
        for (int r = 0; r < 4; ++r) {
          int coa = cob + r;
          if (coa < 75) {
            float f = v[r] + bvp[r];
            if (coa < 50) dsto[(size_t)coa * HW + gpix] = f;
            else          dstw[(size_t)(coa - 50) * HW + gpix] = f;
          }
        }
      }
    }
  }
}

// ---------------------------------------------------------------------------
// Small fp32 extractor conv (planar), batched over z = frame*2 + batch
// ---------------------------------------------------------------------------
template<int CIN>
__global__ __launch_bounds__(256) void conv_fr_k(
    const float* __restrict__ sA, const float* __restrict__ sB, int mode,
    const float* __restrict__ wgt, const float* __restrict__ bias,
    float* __restrict__ dst)
{
  const int z = blockIdx.y;
  const float* src = (mode == 0)
      ? (((z >> 1) ? sB : sA) + (size_t)(z & 1) * 3 * HW)
      : (sA + (size_t)z * 16 * HW);
  float* out = dst + (size_t)z * 16 * HW;

  const int sp = blockIdx.x;
  const int bx = (sp & 7) * 32, by = (sp >> 3) * 32;
  const int tid = threadIdx.x;
  const int tx = tid & 15, ty = tid >> 4;

  __shared__ float s_in[CIN_TILE][34][36];
  float acc[16][2][2];
#pragma unroll
  for (int co = 0; co < 16; ++co) {
    acc[co][0][0] = 0.f; acc[co][0][1] = 0.f;
    acc[co][1][0] = 0.f; acc[co][1][1] = 0.f;
  }

  for (int c0 = 0; c0 < CIN; c0 += CIN_TILE) {
    __syncthreads();
    const int nst = CIN_TILE * 34 * 34;
    for (int i = tid; i < nst; i += 256) {
      int ci = i / (34 * 34);
      int r = i - ci * (34 * 34);
      int yy = r / 34;
      int xx = r - yy * 34;
      int gy = by + yy - 1, gx = bx + xx - 1;
      int cc = c0 + ci;
      float v = 0.f;
      if (cc < CIN && (unsigned)gy < (unsigned)H && (unsigned)gx < (unsigned)W)
        v = src[(size_t)cc * HW + gy * W + gx];
      s_in[ci][yy][xx] = v;
    }
    __syncthreads();

    const int cmax = (CIN - c0 < CIN_TILE) ? (CIN - c0) : CIN_TILE;
    for (int ci = 0; ci < cmax; ++ci) {
      float win[4][4];
#pragma unroll
      for (int iy = 0; iy < 4; ++iy)
#pragma unroll
        for (int ix = 0; ix < 4; ++ix)
          win[iy][ix] = s_in[ci][2 * ty + iy][2 * tx + ix];
#pragma unroll
      for (int co = 0; co < 16; ++co) {
        const float* wp = wgt + ((size_t)co * CIN + (c0 + ci)) * 9;
        float w0 = wp[0], w1 = wp[1], w2 = wp[2];
        float w3 = wp[3], w4 = wp[4], w5 = wp[5];
        float w6 = wp[6], w7 = wp[7], w8 = wp[8];
#pragma unroll
        for (int py = 0; py < 2; ++py)
#pragma unroll
          for (int px = 0; px < 2; ++px) {
            float s = acc[co][py][px];
            s += w0 * win[py + 0][px + 0];
            s += w1 * win[py + 0][px + 1];
            s += w2 * win[py + 0][px + 2];
            s += w3 * win[py + 1][px + 0];
            s += w4 * win[py + 1][px + 1];
            s += w5 * win[py + 1][px + 2];
            s += w6 * win[py + 2][px + 0];
            s += w7 * win[py + 2][px + 1];
            s += w8 * win[py + 2][px + 2];
            acc[co][py][px] = s;
          }
      }
    }
  }
#pragma unroll
  for (int co = 0; co < 16; ++co) {
    float bv = bias[co];
#pragma unroll
    for (int py = 0; py < 2; ++py)
#pragma unroll
      for (int px = 0; px < 2; ++px)
        out[(size_t)co * HW + (size_t)(by + 2 * ty + py) * W + (bx + 2 * tx + px)] =
            lrelu_f(acc[co][py][px] + bv);
  }
}

// ---------------------------------------------------------------------------
// Build combined NHWC bf16 [HW][288] for batch item b
// ---------------------------------------------------------------------------
__global__ __launch_bounds__(256) void pack_k(
    const float* __restrict__ feat1, const float* __restrict__ feat2,
    const float* __restrict__ corr, const float* __restrict__ fr,
    ushort* __restrict__ comb, int b)
{
  int gid = blockIdx.x * 256 + threadIdx.x;   // over 9*HW
  int chunk = gid / HW;
  int p = gid - chunk * HW;
  int c0 = chunk * 32;

  uint u[16];
#pragma unroll
  for (int j = 0; j < 32; j += 2) {
    float f[2];
#pragma unroll
    for (int q = 0; q < 2; ++q) {
      int cc = c0 + j + q;
      float v;
      if (cc < 32)       v = feat1[(size_t)(b * 32 + cc) * HW + p];
      else if (cc < 64)  v = feat2[(size_t)(b * 32 + cc - 32) * HW + p];
      else if (cc < 233) v = corr[(size_t)(b * 169 + cc - 64) * HW + p];
      else if (cc < 249) v = fr[(size_t)(b * 16 + (cc - 233)) * HW + p];
      else if (cc < 265) v = fr[(size_t)((2 + b) * 16 + (cc - 249)) * HW + p];
      else if (cc == 265) v = 0.5f;
      else               v = 0.f;
      f[q] = v;
    }
    u[j >> 1] = (uint)f2bf(f[0]) | ((uint)f2bf(f[1]) << 16);
  }
  uint4* dst = (uint4*)&comb[(size_t)p * 288 + c0];
#pragma unroll
  for (int q = 0; q < 4; ++q) {
    uint4 t;
    t.x = u[q * 4 + 0]; t.y = u[q * 4 + 1]; t.z = u[q * 4 + 2]; t.w = u[q * 4 + 3];
    dst[q] = t;
  }
}

// ---------------------------------------------------------------------------
// Fused weight prep: all conv weight transforms in one launch.
// ---------------------------------------------------------------------------
struct PrepSeg { const float* src; ushort* dst; int O, I, Ipad; };
struct PrepArgs { PrepSeg s[13]; int pre[14]; };

__global__ __launch_bounds__(256) void prep_all_k(PrepArgs a)
{
  int gid = blockIdx.x * 256 + threadIdx.x;
  if (gid >= a.pre[13]) return;
  int si = 0;
  while (gid >= a.pre[si + 1]) ++si;
  int idx = gid - a.pre[si];
  const PrepSeg sg = a.s[si];
  int i = idx % sg.Ipad;
  int r = idx / sg.Ipad;
  int tap = r % 9;
  int o = r / 9;
  float v = (i < sg.I) ? sg.src[((size_t)o * sg.I + i) * 9 + tap] : 0.f;
  sg.dst[idx] = f2bf(v);
}

// fused bias copies: contiguous per-path bias buffers + head bias build
__global__ __launch_bounds__(256) void bias_all_k(
    const float* kb1_0, const float* kb1_1, const float* kb2_0, const float* kb2_1,
    const float* kb3_0, const float* kb3_1,
    const float* ob0, const float* wb0, const float* ob1, const float* wb1,
    float* bb1, float* bb2, float* bb3, float* bbh)
{
  int yq = blockIdx.y;
  int i = threadIdx.x;
  switch (yq) {
    case 0: bb1[i] = kb1_0[i]; break;
    case 1: bb1[256 + i] = kb1_1[i]; break;
    case 2: bb2[i] = kb2_0[i]; break;
    case 3: bb2[256 + i] = kb2_1[i]; break;
    case 4: if (i < 128) bb3[i] = kb3_0[i]; break;
    case 5: if (i < 128) bb3[128 + i] = kb3_1[i]; break;
    case 6: if (i < 128) bbh[i]       = (i < 50) ? ob0[i] : ((i < 75) ? wb0[i - 50] : 0.f); break;
    case 7: if (i < 128) bbh[128 + i] = (i < 50) ? ob1[i] : ((i < 75) ? wb1[i - 50] : 0.f); break;
  }
}

// blend second conv: NHWC bf16 64ch -> sigmoid fp32 planar
__global__ __launch_bounds__(256) void blend2_k(
    const ushort* __restrict__ actD, const float* __restrict__ wgt,
    const float* __restrict__ b2, float* __restrict__ outp)
{
  int p = blockIdx.x * 256 + threadIdx.x;
  int y = p >> 8, x = p & 255;
  float acc = b2[0];
  for (int dy = -1; dy <= 1; ++dy) {
    int gy = y + dy;
    if ((unsigned)gy >= (unsigned)H) continue;
    for (int dx = -1; dx <= 1; ++dx) {
      int gx = x + dx;
      if ((unsigned)gx >= (unsigned)W) continue;
      int tap = (dy + 1) * 3 + (dx + 1);
      const ushort* rowp = actD + (size_t)(gy * W + gx) * 64;
#pragma unroll
      for (int c8 = 0; c8 < 8; ++c8) {
        uint4 v = *(const uint4*)&rowp[c8 * 8];
        const uint* vv = &v.x;
#pragma unroll
        for (int q = 0; q < 4; ++q) {
          float f0 = __uint_as_float(vv[q] << 16);
          float f1 = __uint_as_float(vv[q] & 0xFFFF0000u);
          int ci = c8 * 8 + q * 2;
          acc += f0 * wgt[ci * 9 + tap];
          acc += f1 * wgt[(ci + 1) * 9 + tap];
        }
      }
    }
  }
  outp[p] = 1.f / (1.f + expf(-acc));
}

// softmax over 25 channels, both paths in one launch (grid.y = path)
__global__ __launch_bounds__(256) void softmax25_k(float* __restrict__ w1,
                                                   float* __restrict__ w2)
{
  float* wr = blockIdx.y ? w2 : w1;
  int p = blockIdx.x * 256 + threadIdx.x;
  if (p >= HW) return;
  float v[25];
  float m = -1e30f;
#pragma unroll
  for (int k = 0; k < 25; ++k) {
    v[k] = wr[(size_t)k * HW + p];
    m = fmaxf(m, v[k]);
  }
  float s = 0.f;
#pragma unroll
  for (int k = 0; k < 25; ++k) {
    v[k] = expf(v[k] - m);
    s += v[k];
  }
  float inv = 1.f / s;
#pragma unroll
  for (int k = 0; k < 25; ++k)
    wr[(size_t)k * HW + p] = v[k] * inv;
}

__device__ __forceinline__ void cubic4(float t, float* cw)
{
  const float A_ = -0.75f;
  float t2 = t * t;
  cw[1] = ((A_ + 2.f) * t - (A_ + 3.f)) * t2 + 1.f;
  float s = 1.f - t;
  cw[2] = ((A_ + 2.f) * s - (A_ + 3.f)) * (s * s) + 1.f;
  float u = t + 1.f;
  cw[0] = ((A_ * u - 5.f * A_) * u + 8.f * A_) * u - 4.f * A_;
  float v = 2.f - t;
  cw[3] = ((A_ * v - 5.f * A_) * v + 8.f * A_) * v - 4.f * A_;
}

// ---------------------------------------------------------------------------
// AdaCoF sampling + blend, LDS-tiled.  Block = 256 thr, tile 64x4 px,
// halo 8; both frames staged as float4 (3ch+pad) -> 51.2 KB LDS.
// ---------------------------------------------------------------------------
#define ATW 64
#define ATH 4
#define AHL 8
#define AROWS (ATH + 2*AHL)   // 20
#define ACOLS (ATW + 2*AHL)   // 80

__global__ __launch_bounds__(256) void adacof_final_k(
    const float* __restrict__ frame1, const float* __restrict__ frame2,
    const float* __restrict__ off1, const float* __restrict__ off2,
    const float* __restrict__ wt1, const float* __restrict__ wt2,
    const float* __restrict__ blend, float* __restrict__ outp)
{
  __shared__ __align__(16) float4 s_img[2 * AROWS * ACOLS];   // 51.2 KB

  const int tid = threadIdx.x;
  int t = blockIdx.x;
  const int tilesPerImg = (H / ATH) * (W / ATW);   // 256
  const int b = t / tilesPerImg; t -= b * tilesPerImg;
  const int by = (t >> 2) * ATH, bx = (t & 3) * ATW;
  const int ty = tid >> 6, txx = tid & 63;
  const int y = by + ty, x = bx + txx;
  const int p = y * W + x;
  const int tx0 = bx - AHL, ty0 = by - AHL;

  const float* f1 = frame1 + (size_t)b * 3 * HW;
  const float* f2 = frame2 + (size_t)b * 3 * HW;

  for (int i = tid; i < AROWS * ACOLS; i += 256) {
    int r = i / ACOLS, cc = i - r * ACOLS;
    int gy = min(max(ty0 + r, 0), H - 1);
    int gx = min(max(tx0 + cc, 0), W - 1);
    int q = gy * W + gx;
    float4 v1, v2;
    v1.x = f1[q]; v1.y = f1[HW + q]; v1.z = f1[2 * HW + q]; v1.w = 0.f;
    v2.x = f2[q]; v2.y = f2[HW + q]; v2.z = f2[2 * HW + q]; v2.w = 0.f;
    s_img[i] = v1;
    s_img[AROWS * ACOLS + i] = v2;
  }
  __syncthreads();

  float a1[3] = {0.f, 0.f, 0.f};
  float a2[3] = {0.f, 0.f, 0.f};

  const size_t ob1 = (size_t)b * 50 * HW, wb1 = (size_t)b * 25 * HW;

#pragma unroll 2
  for (int k = 0; k < 25; ++k) {
#pragma unroll
    for (int fr = 0; fr < 2; ++fr) {
      const float* off = fr ? off2 : off1;
      const float* wts = fr ? wt2 : wt1;
      const float* img = fr ? f2 : f1;
      float* acc = fr ? a2 : a1;

      float dx = off[ob1 + (size_t)(2 * k) * HW + p];
      float dy = off[ob1 + (size_t)(2 * k + 1) * HW + p];
      float wk = wts[wb1 + (size_t)k * HW + p];
      float sx = (float)x + dx, sy = (float)y + dy;
      float x0f = floorf(sx), y0f = floorf(sy);
      float tx = sx - x0f, tyf = sy - y0f;
      float wx[4], wy[4];
      cubic4(tx, wx);
      cubic4(tyf, wy);
      int ix0 = (int)x0f, iy0 = (int)y0f;

      bool inT = (ix0 - 1 >= tx0) && (ix0 + 2 <= tx0 + ACOLS - 1) &&
                 (iy0 - 1 >= ty0) && (iy0 + 2 <= ty0 + AROWS - 1);
      if (__builtin_expect(inT, 1)) {
        const float4* base = &s_img[(size_t)fr * AROWS * ACOLS +
                                    (iy0 - 1 - ty0) * ACOLS + (ix0 - 1 - tx0)];
#pragma unroll
        for (int i = 0; i < 4; ++i) {
#pragma unroll
          for (int j = 0; j < 4; ++j) {
            float wf = wy[i] * wx[j] * wk;
            float4 v = base[i * ACOLS + j];
            acc[0] += v.x * wf;
            acc[1] += v.y * wf;
            acc[2] += v.z * wf;
          }
        }
      } else {
        int xi[4], yi[4];
#pragma unroll
        for (int i = 0; i < 4; ++i) {
          xi[i] = min(max(ix0 + i - 1, 0), W - 1);
          yi[i] = min(max(iy0 + i - 1, 0), H - 1);
        }
#pragma unroll
        for (int i = 0; i < 4; ++i) {
#pragma unroll
          for (int j = 0; j < 4; ++j) {
            float wf = wy[i] * wx[j] * wk;
            int q = yi[i] * W + xi[j];
            acc[0] += img[q] * wf;
            acc[1] += img[HW + q] * wf;
            acc[2] += img[2 * HW + q] * wf;
          }
        }
      }
    }
  }

  float bl = blend[(size_t)b * HW + p];
#pragma unroll
  for (int c3 = 0; c3 < 3; ++c3)
    outp[((size_t)b * 3 + c3) * HW + p] = bl * a1[c3] + (1.f - bl) * a2[c3];
}

// ---------------------------------------------------------------------------
extern "C" void kernel_launch(void* const* d_in, const int* in_sizes, int n_in,
                              void* d_out, int out_size, void* d_ws, size_t ws_size,
                              hipStream_t stream)
{
  const float* frame1 = (const float*)d_in[0];
  const float* frame2 = (const float*)d_in[1];
  const float* feat1  = (const float*)d_in[2];
  const float* feat2  = (const float*)d_in[3];
  const float* corr   = (const float*)d_in[4];
  const float* fr_w1  = (const float*)d_in[5];
  const float* fr_b1  = (const float*)d_in[6];
  const float* fr_w2  = (const float*)d_in[7];
  const float* fr_b2  = (const float*)d_in[8];

  const float* kw1[2] = {(const float*)d_in[9],  (const float*)d_in[19]};
  const float* kb1[2] = {(const float*)d_in[10], (const float*)d_in[20]};
  const float* kw2[2] = {(const float*)d_in[11], (const float*)d_in[21]};
  const float* kb2[2] = {(const float*)d_in[12], (const float*)d_in[22]};
  const float* kw3[2] = {(const float*)d_in[13], (const float*)d_in[23]};
  const float* kb3[2] = {(const float*)d_in[14], (const float*)d_in[24]};
  const float* kow[2] = {(const float*)d_in[15], (const float*)d_in[25]};
  const float* kob[2] = {(const float*)d_in[16], (const float*)d_in[26]};
  const float* kww[2] = {(const float*)d_in[17], (const float*)d_in[27]};
  const float* kwb[2] = {(const float*)d_in[18], (const float*)d_in[28]};

  const float* bl_w1 = (const float*)d_in[29];
  const float* bl_b1 = (const float*)d_in[30];
  const float* bl_w2 = (const float*)d_in[31];
  const float* bl_b2 = (const float*)d_in[32];

  float* out = (float*)d_out;
  float* o_out   = out;
  float* o_blend = o_out   + (size_t)BATCH * 3 * HW;
  float* o_off1  = o_blend + (size_t)BATCH * 1 * HW;
  float* o_off2  = o_off1  + (size_t)BATCH * 50 * HW;
  float* o_w1    = o_off2  + (size_t)BATCH * 50 * HW;
  float* o_w2    = o_w1    + (size_t)BATCH * 25 * HW;

  // allow 152 KB dynamic LDS on the conv kernels (capture-safe, idempotent)
  hipFuncSetAttribute((const void*)convmm_k<0>,
                      hipFuncAttributeMaxDynamicSharedMemorySize, DYN_LDS_BYTES);
  hipFuncSetAttribute((const void*)convmm_k<1>,
                      hipFuncAttributeMaxDynamicSharedMemorySize, DYN_LDS_BYTES);

  // ---- workspace layout (sizes all multiples of 256 B) ----
  size_t off = 0;
  char* wsb = (char*)d_ws;
  auto alloc = [&](size_t bytes) -> void* {
    void* pp = wsb + off;
    off += (bytes + 255) & ~(size_t)255;
    return pp;
  };
  const size_t NEED_MERGED = 212700000;
  const bool merged = ws_size >= NEED_MERGED;
  const int NZ = merged ? 2 : 1;

  ushort* zpage = (ushort*)alloc(512);
  ushort* wp1   = (ushort*)alloc((size_t)2 * 256 * 9 * 288 * 2);
  ushort* wp2   = (ushort*)alloc((size_t)2 * 256 * 9 * 256 * 2);
  ushort* wp3   = (ushort*)alloc((size_t)2 * 128 * 9 * 256 * 2);
  ushort* wph   = (ushort*)alloc((size_t)2 * 128 * 9 * 128 * 2);
  ushort* wpb   = (ushort*)alloc((size_t)64 * 9 * 288 * 2);
  float*  bb1   = (float*)alloc(2 * 256 * 4);
  float*  bb2   = (float*)alloc(2 * 256 * 4);
  float*  bb3   = (float*)alloc(2 * 128 * 4);
  float*  bbh   = (float*)alloc(2 * 128 * 4);
  float*  tmp4  = (float*)alloc((size_t)4 * 16 * HW * 4);
  float*  frbuf = (float*)alloc((size_t)4 * 16 * HW * 4);
  ushort* comb  = (ushort*)alloc((size_t)HW * 288 * 2);
  ushort* actA  = (ushort*)alloc((size_t)NZ * HW * 256 * 2);
  ushort* actB  = (ushort*)alloc((size_t)NZ * HW * 256 * 2);

  dim3 blk(256);
  dim3 cblk(512);

  // ---- fused prep ----
  hipMemsetAsync(zpage, 0, 512, stream);
  {
    PrepArgs pa;
    const int W1 = 256 * 9 * 288, W2 = 256 * 9 * 256, W3 = 128 * 9 * 256;
    const int OW = 50 * 9 * 128, WW = 25 * 9 * 128, ZW = 53 * 9 * 128;
    const int WB = 64 * 9 * 288;
    const int HP = 128 * 9 * 128;
    PrepSeg segs[13] = {
      {kw1[0], wp1,                    256, 266, 288},
      {kw1[1], wp1 + W1,               256, 266, 288},
      {kw2[0], wp2,                    256, 256, 256},
      {kw2[1], wp2 + W2,               256, 256, 256},
      {kw3[0], wp3,                    128, 256, 256},
      {kw3[1], wp3 + W3,               128, 256, 256},
      {kow[0], wph,                     50, 128, 128},
      {kww[0], wph + OW,                25, 128, 128},
      {nullptr, wph + OW + WW,          53,   0, 128},
      {kow[1], wph + HP,                50, 128, 128},
      {kww[1], wph + HP + OW,           25, 128, 128},
      {nullptr, wph + HP + OW + WW,     53,   0, 128},
      {bl_w1,  wpb,                     64, 266, 288},
    };
    int tots[13] = {W1, W1, W2, W2, W3, W3, OW, WW, ZW, OW, WW, ZW, WB};
    pa.pre[0] = 0;
    for (int s = 0; s < 13; ++s) { pa.s[s] = segs[s]; pa.pre[s + 1] = pa.pre[s] + tots[s]; }
    int nblk = (pa.pre[13] + 255) / 256;
    prep_all_k<<<dim3(nblk), blk, 0, stream>>>(pa);
  }
  bias_all_k<<<dim3(1, 8), blk, 0, stream>>>(kb1[0], kb1[1], kb2[0], kb2[1],
                                             kb3[0], kb3[1], kob[0], kwb[0],
                                             kob[1], kwb[1], bb1, bb2, bb3, bbh);

  // ---- frame extractor ----
  conv_fr_k<3><<<dim3(64, 4), blk, 0, stream>>>(frame1, frame2, 0, fr_w1, fr_b1, tmp4);
  conv_fr_k<16><<<dim3(64, 4), blk, 0, stream>>>(tmp4, nullptr, 1, fr_w2, fr_b2, frbuf);

  const int W1 = 256 * 9 * 288, W2 = 256 * 9 * 256, W3 = 128 * 9 * 256;
  const int HP = 128 * 9 * 128;

  for (int b = 0; b < BATCH; ++b) {
    pack_k<<<dim3(9 * HW / 256), blk, 0, stream>>>(feat1, feat2, corr, frbuf, comb, b);

    for (int pp = 0; pp < 2 / NZ; ++pp) {
      const size_t po = pp;
      convmm_k<0><<<dim3(128, 4, NZ), cblk, DYN_LDS_BYTES, stream>>>(
          comb, wp1 + po * W1, bb1 + po * 256, actA + po * (size_t)HW * 256,
          nullptr, nullptr, zpage, 288, 256, 0, W1, 256, HW * 256);
      convmm_k<0><<<dim3(128, 4, NZ), cblk, DYN_LDS_BYTES, stream>>>(
          actA + po * (size_t)HW * 256, wp2 + po * W2, bb2 + po * 256,
          actB + po * (size_t)HW * 256,
          nullptr, nullptr, zpage, 256, 256, HW * 256, W2, 256, HW * 256);
      convmm_k<0><<<dim3(128, 2, NZ), cblk, DYN_LDS_BYTES, stream>>>(
          actB + po * (size_t)HW * 256, wp3 + po * W3, bb3 + po * 128,
          actA + po * (size_t)HW * 128,
          nullptr, nullptr, zpage, 256, 128, HW * 256, W3, 128, HW * 128);
      convmm_k<1><<<dim3(128, 2, NZ), cblk, DYN_LDS_BYTES, stream>>>(
          actA + po * (size_t)HW * 128, wph + po * HP, bbh + po * 128, nullptr,
          o_off1 + (size_t)b * 50 * HW + po * (size_t)BATCH * 50 * HW,
          o_w1 + (size_t)b * 25 * HW + po * (size_t)BATCH * 25 * HW,
          zpage, 128, 0, HW * 128, HP, 128, 0);
    }
    softmax25_k<<<dim3(HW / 256, 2), blk, 0, stream>>>(
        o_w1 + (size_t)b * 25 * HW, o_w2 + (size_t)b * 25 * HW);

    convmm_k<0><<<dim3(128, 1, 1), cblk, DYN_LDS_BYTES, stream>>>(
        comb, wpb, bl_b1, actB, nullptr, nullptr, zpage, 288, 64, 0, 0, 0, 0);
    blend2_k<<<dim3(HW / 256), blk, 0, stream>>>(actB, bl_w2, bl_b2,
                                                 o_blend + (size_t)b * HW);
  }

  adacof_final_k<<<dim3(BATCH * (H / ATH) * (W / ATW)), blk, 0, stream>>>(
      frame1, frame2, o_off1, o_off2, o_w1, o_w2, o_blend, o_out);
}